// Round 4
// baseline (811.363 us; speedup 1.0000x reference)
//
#include <hip/hip_runtime.h>
#include <hip/hip_bf16.h>
#include <stdint.h>

using bf16 = __hip_bfloat16;
typedef __attribute__((ext_vector_type(8))) short bf16x8;
typedef __attribute__((ext_vector_type(4))) float f32x4;
typedef __attribute__((ext_vector_type(8))) unsigned short ushort8;

#define MFMA16(a,b,c) __builtin_amdgcn_mfma_f32_16x16x32_bf16(a,b,c,0,0,0)

static constexpr int Bc = 4, Sc = 2048, HSc = 2048, Hc = 16, KVc = 8, Dc = 128;

__device__ __forceinline__ void gl_lds16(const void* g, void* l) {
  __builtin_amdgcn_global_load_lds((const __attribute__((address_space(1))) uint32_t*)g,
                                   (__attribute__((address_space(3))) uint32_t*)l, 16, 0, 0);
}

__device__ __forceinline__ unsigned short f2bf(float f) {
  bf16 h = __float2bfloat16(f);
  return *reinterpret_cast<unsigned short*>(&h);
}

// ---------------- fused fp32 -> bf16 convert (all 5 regions, one launch) ----------------
__global__ __launch_bounds__(256) void cvt_all(const float* __restrict__ x,
                                               const float* __restrict__ wq,
                                               const float* __restrict__ wk,
                                               const float* __restrict__ wv,
                                               const float* __restrict__ wo,
                                               unsigned short* __restrict__ xb,
                                               unsigned short* __restrict__ wqkv,
                                               unsigned short* __restrict__ wob) {
  const int NX = 2097152, NQ = 524288, NK = 262144, NV = 262144, NO = 524288;
  const int T = NX + NQ + NK + NV + NO;
  int stride = gridDim.x * blockDim.x;
  for (int i = blockIdx.x * blockDim.x + threadIdx.x; i < T; i += stride) {
    const float* s;
    unsigned short* d;
    int j = i;
    if (j < NX) { s = x; d = xb; }
    else if ((j -= NX) < NQ) { s = wq; d = wqkv; }
    else if ((j -= NQ) < NK) { s = wk; d = wqkv + (size_t)NQ * 8; }
    else if ((j -= NK) < NV) { s = wv; d = wqkv + (size_t)(NQ + NK) * 8; }
    else { j -= NV; s = wo; d = wob; }
    const float4 a = *(const float4*)(s + (size_t)j * 8);
    const float4 b = *(const float4*)(s + (size_t)j * 8 + 4);
    ushort8 o;
    o[0] = f2bf(a.x); o[1] = f2bf(a.y); o[2] = f2bf(a.z); o[3] = f2bf(a.w);
    o[4] = f2bf(b.x); o[5] = f2bf(b.y); o[6] = f2bf(b.z); o[7] = f2bf(b.w);
    *(ushort8*)(d + (size_t)j * 8) = o;
  }
}

// ---------------- GEMM: C[M][N] = A[M][K] * B[N][K]^T ----------------
// m97 structure + XCD-chunked 2D super-tile swizzle for L2 locality.
__device__ __forceinline__ void storeC(float* C, size_t i, float v) { C[i] = v; }
__device__ __forceinline__ void storeC(bf16* C, size_t i, float v) { C[i] = __float2bfloat16(v); }

template <typename OUT_T>
__global__ __launch_bounds__(256) void gemm_bt(const bf16* __restrict__ A,
                                               const bf16* __restrict__ B,
                                               OUT_T* __restrict__ C,
                                               int M, int N, int K,
                                               int gm, int gn, int rbm, int rbn) {
  const int nwg = gridDim.x;
  const int cpx = nwg >> 3;
  const int swz = (blockIdx.x & 7) * cpx + (blockIdx.x >> 3);
  const int rsz = rbm * rbn;
  const int region = swz / rsz, rid = swz % rsz;
  const int regions_n = gn / rbn;
  const int bm = (region / regions_n) * rbm + rid / rbn;
  const int bn = (region % regions_n) * rbn + rid % rbn;

  __shared__ __align__(16) bf16 sA[128][64];
  __shared__ __align__(16) bf16 sB[128][64];
  const int tid = threadIdx.x;
  const int lane = tid & 63;
  const int wave = tid >> 6;
  const int wr = wave >> 1, wc = wave & 1;
  const int lg = lane >> 4, lr = lane & 15;

  f32x4 acc[4][4];
  #pragma unroll
  for (int m = 0; m < 4; ++m)
    #pragma unroll
    for (int n = 0; n < 4; ++n) acc[m][n] = (f32x4){0.f, 0.f, 0.f, 0.f};

  const int rowA = bm * 128;
  const int rowB = bn * 128;

  for (int k0 = 0; k0 < K; k0 += 64) {
    #pragma unroll
    for (int it = 0; it < 4; ++it) {
      int idx = it * 256 + tid;
      int r = idx >> 3, ch = idx & 7;
      gl_lds16(A + (size_t)(rowA + r) * K + k0 + ch * 8, &sA[r][ch * 8]);
      gl_lds16(B + (size_t)(rowB + r) * K + k0 + ch * 8, &sB[r][ch * 8]);
    }
    __syncthreads();
    #pragma unroll
    for (int kk = 0; kk < 2; ++kk) {
      bf16x8 af[4], bfr[4];
      #pragma unroll
      for (int m = 0; m < 4; ++m)
        af[m] = *(const bf16x8*)&sA[wr * 64 + m * 16 + lr][kk * 32 + lg * 8];
      #pragma unroll
      for (int n = 0; n < 4; ++n)
        bfr[n] = *(const bf16x8*)&sB[wc * 64 + n * 16 + lr][kk * 32 + lg * 8];
      #pragma unroll
      for (int m = 0; m < 4; ++m)
        #pragma unroll
        for (int n = 0; n < 4; ++n)
          acc[m][n] = MFMA16(af[m], bfr[n], acc[m][n]);
    }
    __syncthreads();
  }
  #pragma unroll
  for (int m = 0; m < 4; ++m)
    #pragma unroll
    for (int n = 0; n < 4; ++n)
      #pragma unroll
      for (int r = 0; r < 4; ++r) {
        size_t row = rowA + wr * 64 + m * 16 + lg * 4 + r;
        size_t col = rowB + wc * 64 + n * 16 + lr;
        storeC(C, row * (size_t)N + col, acc[m][n][r]);
      }
}

// ---------------- RMSNorm + RoPE on Q and K ----------------
__global__ __launch_bounds__(256) void norm_rope(const bf16* __restrict__ qkv,
                                                 const float* __restrict__ cosT,
                                                 const float* __restrict__ sinT,
                                                 const float* __restrict__ qw,
                                                 const float* __restrict__ kw,
                                                 bf16* __restrict__ Qn, bf16* __restrict__ Kn) {
  const int bs = blockIdx.x;
  const int s = bs & (Sc - 1);
  const int b = bs >> 11;
  const int wave = threadIdx.x >> 6, lane = threadIdx.x & 63;
  const float c0 = cosT[(size_t)s * Dc + lane];
  const float c1 = cosT[(size_t)s * Dc + 64 + lane];
  const float s0 = sinT[(size_t)s * Dc + lane];
  const float s1 = sinT[(size_t)s * Dc + 64 + lane];
  const bf16* row = qkv + (size_t)bs * 4096;
  #pragma unroll
  for (int i = 0; i < 6; ++i) {
    int head = wave * 6 + i;  // 0..15 = Q heads, 16..23 = K heads
    bool isQ = head < 16;
    int col = head * Dc;
    float x0 = __bfloat162float(row[col + lane]);
    float x1 = __bfloat162float(row[col + 64 + lane]);
    float ss = x0 * x0 + x1 * x1;
    #pragma unroll
    for (int off = 32; off; off >>= 1) ss += __shfl_xor(ss, off);
    float inv = rsqrtf(ss * (1.0f / 128.0f) + 1e-6f);
    const float* w = isQ ? qw : kw;
    float n0 = x0 * inv * w[lane];
    float n1 = x1 * inv * w[lane + 64];
    float o0 = n0 * c0 - n1 * s0;
    float o1 = n1 * c1 + n0 * s1;
    size_t base;
    bf16* dst;
    if (isQ) { base = ((size_t)(b * Hc + head) * Sc + s) * Dc; dst = Qn; }
    else     { base = ((size_t)(b * KVc + (head - 16)) * Sc + s) * Dc; dst = Kn; }
    dst[base + lane] = __float2bfloat16(o0);
    dst[base + 64 + lane] = __float2bfloat16(o1);
  }
}

// ---------------- V transpose: qkv V slice -> Vt [B][KV][D][S] ----------------
__global__ __launch_bounds__(256) void v_transpose(const bf16* __restrict__ qkv,
                                                   bf16* __restrict__ Vt) {
  const int s0 = blockIdx.x * 64;
  const int bk = blockIdx.y;  // b*8+kv
  __shared__ __align__(16) bf16 tile[64][136];
  const int tid = threadIdx.x;
  const size_t srcbase = ((size_t)(bk >> 3) * Sc + s0) * 4096 + 3072 + (size_t)(bk & 7) * Dc;
  #pragma unroll
  for (int it = 0; it < 4; ++it) {
    int idx = it * 256 + tid;
    int r = idx >> 4, ch = idx & 15;
    *(bf16x8*)&tile[r][ch * 8] = *(const bf16x8*)(qkv + srcbase + (size_t)r * 4096 + ch * 8);
  }
  __syncthreads();
  const size_t dstbase = (size_t)bk * Dc * Sc + s0;
  #pragma unroll
  for (int it = 0; it < 4; ++it) {
    int idx = it * 256 + tid;
    int d = idx >> 3, scc = idx & 7;
    bf16x8 o;
    #pragma unroll
    for (int j = 0; j < 8; ++j) o[j] = *(const short*)&tile[scc * 8 + j][d];
    *(bf16x8*)(Vt + dstbase + (size_t)d * Sc + scc * 8) = o;
  }
}

// ---------------- causal GQA flash attention ----------------
// QBLK=128, 8 waves, single-buffered (TLP hides staging), T2 swizzle,
// heavy-first schedule, T5 setprio, T13 defer-max, deferred l-reduction.
__global__ __launch_bounds__(512, 6) void flash_kernel(const bf16* __restrict__ Qn,
                                                       const bf16* __restrict__ Kn,
                                                       const bf16* __restrict__ Vt,
                                                       bf16* __restrict__ Out) {
  const int qi = 15 - (blockIdx.x >> 6);   // heavy-first: big q-tiles launch first
  const int bh = blockIdx.x & 63;
  const int q0 = qi * 128;
  const int b = bh >> 4, h = bh & 15;
  const int kv = h >> 1;
  const int tid = threadIdx.x;
  const int wave = tid >> 6, lane = tid & 63;
  const int lg = lane >> 4, lr = lane & 15;
  const int rm = lr & 7;  // read-side XOR mask

  __shared__ __align__(16) bf16 sK[64][128];   // XOR-swizzled (16B slot ^= row&7)
  __shared__ __align__(16) bf16 sV[128][64];   // [d][s_local], XOR-swizzled
  __shared__ __align__(16) bf16 sP[8][16][72]; // per-wave P

  const int qrow = q0 + wave * 16;             // this wave's 16 q-rows start here
  const bf16* qbase = Qn + ((size_t)(b * Hc + h) * Sc + qrow + lr) * Dc;
  bf16x8 qf[4];
  #pragma unroll
  for (int kk = 0; kk < 4; ++kk) qf[kk] = *(const bf16x8*)(qbase + kk * 32 + lg * 8);

  f32x4 oacc[8];
  #pragma unroll
  for (int i = 0; i < 8; ++i) oacc[i] = (f32x4){0.f, 0.f, 0.f, 0.f};
  float m_run[4], l_run[4];
  #pragma unroll
  for (int r = 0; r < 4; ++r) { m_run[r] = -3.0e38f; l_run[r] = 0.f; }

  const bf16* kb = Kn + ((size_t)(b * KVc + kv) * Sc) * Dc;
  const bf16* vb = Vt + ((size_t)(b * KVc + kv) * Dc) * Sc;
  const float scl = 0.08838834764831845f * 1.4426950408889634f;  // 1/sqrt(D)*log2(e)

  const int nt = 2 * qi + 2;
  for (int t = 0; t < nt; ++t) {
    const int k0 = t * 64;
    // stage K (64x128) and V^T (128x64): linear LDS dest, inverse-swizzled source
    #pragma unroll
    for (int it = 0; it < 2; ++it) {
      int idx = it * 512 + tid;
      int r = idx >> 4, ps = idx & 15;
      int ls = ps ^ (r & 7);
      gl_lds16(kb + (size_t)(k0 + r) * Dc + ls * 8, &sK[r][ps * 8]);
    }
    #pragma unroll
    for (int it = 0; it < 2; ++it) {
      int idx = it * 512 + tid;
      int r = idx >> 3, ps = idx & 7;
      int ls = ps ^ (r & 7);
      gl_lds16(vb + (size_t)r * Sc + k0 + ls * 8, &sV[r][ps * 8]);
    }
    __syncthreads();  // vmcnt(0) drain + barrier: tile staged

    float tt[4][4];
    __builtin_amdgcn_s_setprio(1);
    #pragma unroll
    for (int c = 0; c < 4; ++c) {
      f32x4 sacc = (f32x4){0.f, 0.f, 0.f, 0.f};
      #pragma unroll
      for (int kk = 0; kk < 4; ++kk) {
        bf16x8 kf = *(const bf16x8*)&sK[c * 16 + lr][((kk * 4 + lg) ^ rm) * 8];
        sacc = MFMA16(qf[kk], kf, sacc);
      }
      int kg = k0 + c * 16 + lr;
      #pragma unroll
      for (int r = 0; r < 4; ++r) {
        int qg = qrow + lg * 4 + r;
        tt[c][r] = (kg <= qg) ? sacc[r] * scl : -3.0e38f;
      }
    }
    __builtin_amdgcn_s_setprio(0);

    // row max (16 lanes per row share via xor 1/2/4/8)
    float pmax[4];
    #pragma unroll
    for (int r = 0; r < 4; ++r) {
      float mx = fmaxf(fmaxf(tt[0][r], tt[1][r]), fmaxf(tt[2][r], tt[3][r]));
      mx = fmaxf(mx, __shfl_xor(mx, 1));
      mx = fmaxf(mx, __shfl_xor(mx, 2));
      mx = fmaxf(mx, __shfl_xor(mx, 4));
      mx = fmaxf(mx, __shfl_xor(mx, 8));
      pmax[r] = mx;
    }
    // T13 defer-max: skip rescale while max growth <= 8 (P bounded by 2^8)
    bool grow = (pmax[0] > m_run[0] + 8.f) || (pmax[1] > m_run[1] + 8.f) ||
                (pmax[2] > m_run[2] + 8.f) || (pmax[3] > m_run[3] + 8.f);
    if (__any(grow)) {
      #pragma unroll
      for (int r = 0; r < 4; ++r) {
        float mnew = fmaxf(m_run[r], pmax[r]);
        float alpha = exp2f(m_run[r] - mnew);
        m_run[r] = mnew;
        l_run[r] *= alpha;
        #pragma unroll
        for (int dc = 0; dc < 8; ++dc) oacc[dc][r] *= alpha;
      }
    }
    #pragma unroll
    for (int r = 0; r < 4; ++r) {
      float local = 0.f;
      #pragma unroll
      for (int c = 0; c < 4; ++c) { tt[c][r] = exp2f(tt[c][r] - m_run[r]); local += tt[c][r]; }
      l_run[r] += local;  // per-lane partial; reduced once after the loop
    }
    // per-wave P round-trip (same-wave LDS RAW: lgkmcnt-ordered, no barrier)
    #pragma unroll
    for (int c = 0; c < 4; ++c)
      #pragma unroll
      for (int r = 0; r < 4; ++r)
        sP[wave][lg * 4 + r][c * 16 + lr] = __float2bfloat16(tt[c][r]);

    __builtin_amdgcn_s_setprio(1);
    #pragma unroll
    for (int kk2 = 0; kk2 < 2; ++kk2) {
      bf16x8 pf = *(const bf16x8*)&sP[wave][lr][kk2 * 32 + lg * 8];
      #pragma unroll
      for (int dc = 0; dc < 8; ++dc) {
        bf16x8 vf = *(const bf16x8*)&sV[dc * 16 + lr][((kk2 * 4 + lg) ^ rm) * 8];
        oacc[dc] = MFMA16(pf, vf, oacc[dc]);
      }
    }
    __builtin_amdgcn_s_setprio(0);

    __syncthreads();  // all waves done with sK/sV before next tile overwrites
  }

  #pragma unroll
  for (int r = 0; r < 4; ++r) {
    float l = l_run[r];
    l += __shfl_xor(l, 1);
    l += __shfl_xor(l, 2);
    l += __shfl_xor(l, 4);
    l += __shfl_xor(l, 8);
    l_run[r] = 1.f / l;
  }
  #pragma unroll
  for (int dc = 0; dc < 8; ++dc)
    #pragma unroll
    for (int r = 0; r < 4; ++r) {
      size_t row = (size_t)b * Sc + qrow + lg * 4 + r;
      Out[row * (size_t)(Hc * Dc) + h * Dc + dc * 16 + lr] =
          __float2bfloat16(oacc[dc][r] * l_run[r]);
    }
}

// ---------------- launch ----------------
extern "C" void kernel_launch(void* const* d_in, const int* in_sizes, int n_in,
                              void* d_out, int out_size, void* d_ws, size_t ws_size,
                              hipStream_t stream) {
  const float* x    = (const float*)d_in[0];
  const float* cosT = (const float*)d_in[1];
  const float* sinT = (const float*)d_in[2];
  const float* wq   = (const float*)d_in[3];
  const float* wk   = (const float*)d_in[4];
  const float* wv   = (const float*)d_in[5];
  const float* wo   = (const float*)d_in[6];
  const float* qnw  = (const float*)d_in[7];
  const float* knw  = (const float*)d_in[8];
  float* out = (float*)d_out;

  const size_t MB = 1ull << 20;
  char* ws = (char*)d_ws;
  bf16* xb   = (bf16*)(ws + 0);        // 32MB  [8192][2048]
  bf16* wqkv = (bf16*)(ws + 32 * MB);  // 16MB  [4096][2048]
  bf16* wob  = (bf16*)(ws + 48 * MB);  // 8MB   [2048][2048]
  bf16* qkv  = (bf16*)(ws + 56 * MB);  // 64MB  [8192][4096]
  bf16* Qn   = (bf16*)(ws + 120 * MB); // 32MB  [B][H][S][D]
  bf16* Kn   = (bf16*)(ws + 152 * MB); // 16MB  [B][KV][S][D]
  bf16* Vt   = (bf16*)(ws + 168 * MB); // 16MB  [B][KV][D][S]
  bf16* attn = (bf16*)(ws + 184 * MB); // 32MB  [8192][2048]

  cvt_all<<<2048, 256, 0, stream>>>(x, wq, wk, wv, wo,
                                    (unsigned short*)xb, (unsigned short*)wqkv,
                                    (unsigned short*)wob);

  // QKV GEMM: grid 64x32 blocks -> 1D, region 32x8 (B-slice 4MB/XCD-L2)
  gemm_bt<bf16><<<2048, 256, 0, stream>>>(xb, wqkv, qkv, 8192, 4096, 2048, 64, 32, 32, 8);
  norm_rope<<<8192, 256, 0, stream>>>(qkv, cosT, sinT, qnw, knw, Qn, Kn);
  v_transpose<<<dim3(32, 32), 256, 0, stream>>>(qkv, Vt);
  flash_kernel<<<1024, 512, 0, stream>>>(Qn, Kn, Vt, attn);
  // out GEMM: grid 64x16 -> 1D, region 32x4 (B-slice 2MB)
  gemm_bt<float><<<1024, 256, 0, stream>>>(attn, wob, out, 8192, 2048, 2048, 64, 16, 32, 4);
}

// Round 5
// 486.744 us; speedup vs baseline: 1.6669x; 1.6669x over previous
//
#include <hip/hip_runtime.h>
#include <hip/hip_bf16.h>
#include <stdint.h>

using bf16 = __hip_bfloat16;
typedef __attribute__((ext_vector_type(8))) short bf16x8;
typedef __attribute__((ext_vector_type(4))) float f32x4;
typedef __attribute__((ext_vector_type(8))) unsigned short ushort8;

#define MFMA16(a,b,c) __builtin_amdgcn_mfma_f32_16x16x32_bf16(a,b,c,0,0,0)

static constexpr int Bc = 4, Sc = 2048, HSc = 2048, Hc = 16, KVc = 8, Dc = 128;

__device__ __forceinline__ void gl_lds16(const void* g, void* l) {
  __builtin_amdgcn_global_load_lds((const __attribute__((address_space(1))) uint32_t*)g,
                                   (__attribute__((address_space(3))) uint32_t*)l, 16, 0, 0);
}

__device__ __forceinline__ unsigned short f2bf(float f) {
  bf16 h = __float2bfloat16(f);
  return *reinterpret_cast<unsigned short*>(&h);
}

// ---------------- fused fp32 -> bf16 convert (all 5 regions, one launch) ----------------
__global__ __launch_bounds__(256) void cvt_all(const float* __restrict__ x,
                                               const float* __restrict__ wq,
                                               const float* __restrict__ wk,
                                               const float* __restrict__ wv,
                                               const float* __restrict__ wo,
                                               unsigned short* __restrict__ xb,
                                               unsigned short* __restrict__ wqkv,
                                               unsigned short* __restrict__ wob) {
  const int NX = 2097152, NQ = 524288, NK = 262144, NV = 262144, NO = 524288;
  const int T = NX + NQ + NK + NV + NO;
  int stride = gridDim.x * blockDim.x;
  for (int i = blockIdx.x * blockDim.x + threadIdx.x; i < T; i += stride) {
    const float* s;
    unsigned short* d;
    int j = i;
    if (j < NX) { s = x; d = xb; }
    else if ((j -= NX) < NQ) { s = wq; d = wqkv; }
    else if ((j -= NQ) < NK) { s = wk; d = wqkv + (size_t)NQ * 8; }
    else if ((j -= NK) < NV) { s = wv; d = wqkv + (size_t)(NQ + NK) * 8; }
    else { j -= NV; s = wo; d = wob; }
    const float4 a = *(const float4*)(s + (size_t)j * 8);
    const float4 b = *(const float4*)(s + (size_t)j * 8 + 4);
    ushort8 o;
    o[0] = f2bf(a.x); o[1] = f2bf(a.y); o[2] = f2bf(a.z); o[3] = f2bf(a.w);
    o[4] = f2bf(b.x); o[5] = f2bf(b.y); o[6] = f2bf(b.z); o[7] = f2bf(b.w);
    *(ushort8*)(d + (size_t)j * 8) = o;
  }
}

// ---------------- GEMM: C[M][N] = A[M][K] * B[N][K]^T ----------------
// m97 structure + XCD-chunked 2D super-tile swizzle for L2 locality.
__device__ __forceinline__ void storeC(float* C, size_t i, float v) { C[i] = v; }
__device__ __forceinline__ void storeC(bf16* C, size_t i, float v) { C[i] = __float2bfloat16(v); }

template <typename OUT_T>
__global__ __launch_bounds__(256) void gemm_bt(const bf16* __restrict__ A,
                                               const bf16* __restrict__ B,
                                               OUT_T* __restrict__ C,
                                               int M, int N, int K,
                                               int gm, int gn, int rbm, int rbn) {
  const int nwg = gridDim.x;
  const int cpx = nwg >> 3;
  const int swz = (blockIdx.x & 7) * cpx + (blockIdx.x >> 3);
  const int rsz = rbm * rbn;
  const int region = swz / rsz, rid = swz % rsz;
  const int regions_n = gn / rbn;
  const int bm = (region / regions_n) * rbm + rid / rbn;
  const int bn = (region % regions_n) * rbn + rid % rbn;

  __shared__ __align__(16) bf16 sA[128][64];
  __shared__ __align__(16) bf16 sB[128][64];
  const int tid = threadIdx.x;
  const int lane = tid & 63;
  const int wave = tid >> 6;
  const int wr = wave >> 1, wc = wave & 1;
  const int lg = lane >> 4, lr = lane & 15;

  f32x4 acc[4][4];
  #pragma unroll
  for (int m = 0; m < 4; ++m)
    #pragma unroll
    for (int n = 0; n < 4; ++n) acc[m][n] = (f32x4){0.f, 0.f, 0.f, 0.f};

  const int rowA = bm * 128;
  const int rowB = bn * 128;

  for (int k0 = 0; k0 < K; k0 += 64) {
    #pragma unroll
    for (int it = 0; it < 4; ++it) {
      int idx = it * 256 + tid;
      int r = idx >> 3, ch = idx & 7;
      gl_lds16(A + (size_t)(rowA + r) * K + k0 + ch * 8, &sA[r][ch * 8]);
      gl_lds16(B + (size_t)(rowB + r) * K + k0 + ch * 8, &sB[r][ch * 8]);
    }
    __syncthreads();
    #pragma unroll
    for (int kk = 0; kk < 2; ++kk) {
      bf16x8 af[4], bfr[4];
      #pragma unroll
      for (int m = 0; m < 4; ++m)
        af[m] = *(const bf16x8*)&sA[wr * 64 + m * 16 + lr][kk * 32 + lg * 8];
      #pragma unroll
      for (int n = 0; n < 4; ++n)
        bfr[n] = *(const bf16x8*)&sB[wc * 64 + n * 16 + lr][kk * 32 + lg * 8];
      #pragma unroll
      for (int m = 0; m < 4; ++m)
        #pragma unroll
        for (int n = 0; n < 4; ++n)
          acc[m][n] = MFMA16(af[m], bfr[n], acc[m][n]);
    }
    __syncthreads();
  }
  #pragma unroll
  for (int m = 0; m < 4; ++m)
    #pragma unroll
    for (int n = 0; n < 4; ++n)
      #pragma unroll
      for (int r = 0; r < 4; ++r) {
        size_t row = rowA + wr * 64 + m * 16 + lg * 4 + r;
        size_t col = rowB + wc * 64 + n * 16 + lr;
        storeC(C, row * (size_t)N + col, acc[m][n][r]);
      }
}

// ---------------- RMSNorm + RoPE on Q and K ----------------
__global__ __launch_bounds__(256) void norm_rope(const bf16* __restrict__ qkv,
                                                 const float* __restrict__ cosT,
                                                 const float* __restrict__ sinT,
                                                 const float* __restrict__ qw,
                                                 const float* __restrict__ kw,
                                                 bf16* __restrict__ Qn, bf16* __restrict__ Kn) {
  const int bs = blockIdx.x;
  const int s = bs & (Sc - 1);
  const int b = bs >> 11;
  const int wave = threadIdx.x >> 6, lane = threadIdx.x & 63;
  const float c0 = cosT[(size_t)s * Dc + lane];
  const float c1 = cosT[(size_t)s * Dc + 64 + lane];
  const float s0 = sinT[(size_t)s * Dc + lane];
  const float s1 = sinT[(size_t)s * Dc + 64 + lane];
  const bf16* row = qkv + (size_t)bs * 4096;
  #pragma unroll
  for (int i = 0; i < 6; ++i) {
    int head = wave * 6 + i;  // 0..15 = Q heads, 16..23 = K heads
    bool isQ = head < 16;
    int col = head * Dc;
    float x0 = __bfloat162float(row[col + lane]);
    float x1 = __bfloat162float(row[col + 64 + lane]);
    float ss = x0 * x0 + x1 * x1;
    #pragma unroll
    for (int off = 32; off; off >>= 1) ss += __shfl_xor(ss, off);
    float inv = rsqrtf(ss * (1.0f / 128.0f) + 1e-6f);
    const float* w = isQ ? qw : kw;
    float n0 = x0 * inv * w[lane];
    float n1 = x1 * inv * w[lane + 64];
    float o0 = n0 * c0 - n1 * s0;
    float o1 = n1 * c1 + n0 * s1;
    size_t base;
    bf16* dst;
    if (isQ) { base = ((size_t)(b * Hc + head) * Sc + s) * Dc; dst = Qn; }
    else     { base = ((size_t)(b * KVc + (head - 16)) * Sc + s) * Dc; dst = Kn; }
    dst[base + lane] = __float2bfloat16(o0);
    dst[base + 64 + lane] = __float2bfloat16(o1);
  }
}

// ---------------- V transpose: qkv V slice -> Vt [B][KV][D][S] ----------------
__global__ __launch_bounds__(256) void v_transpose(const bf16* __restrict__ qkv,
                                                   bf16* __restrict__ Vt) {
  const int s0 = blockIdx.x * 64;
  const int bk = blockIdx.y;  // b*8+kv
  __shared__ __align__(16) bf16 tile[64][136];
  const int tid = threadIdx.x;
  const size_t srcbase = ((size_t)(bk >> 3) * Sc + s0) * 4096 + 3072 + (size_t)(bk & 7) * Dc;
  #pragma unroll
  for (int it = 0; it < 4; ++it) {
    int idx = it * 256 + tid;
    int r = idx >> 4, ch = idx & 15;
    *(bf16x8*)&tile[r][ch * 8] = *(const bf16x8*)(qkv + srcbase + (size_t)r * 4096 + ch * 8);
  }
  __syncthreads();
  const size_t dstbase = (size_t)bk * Dc * Sc + s0;
  #pragma unroll
  for (int it = 0; it < 4; ++it) {
    int idx = it * 256 + tid;
    int d = idx >> 3, scc = idx & 7;
    bf16x8 o;
    #pragma unroll
    for (int j = 0; j < 8; ++j) o[j] = *(const short*)&tile[scc * 8 + j][d];
    *(bf16x8*)(Vt + dstbase + (size_t)d * Sc + scc * 8) = o;
  }
}

// ---------------- causal GQA flash attention ----------------
// QBLK=128, 8 waves, single-buffered (TLP hides staging), T2 swizzle,
// heavy-first schedule, T5 setprio, T13 defer-max, deferred l-reduction.
// launch_bounds(512,4): VGPR cap 128 fits the ~110-reg live set (no spill);
// (512,6)'s 85-reg cap spilled everything -> 816MB scratch writes (round-4 lesson).
__global__ __launch_bounds__(512, 4) void flash_kernel(const bf16* __restrict__ Qn,
                                                       const bf16* __restrict__ Kn,
                                                       const bf16* __restrict__ Vt,
                                                       bf16* __restrict__ Out) {
  const int qi = 15 - (blockIdx.x >> 6);   // heavy-first: big q-tiles launch first
  const int bh = blockIdx.x & 63;
  const int q0 = qi * 128;
  const int b = bh >> 4, h = bh & 15;
  const int kv = h >> 1;
  const int tid = threadIdx.x;
  const int wave = tid >> 6, lane = tid & 63;
  const int lg = lane >> 4, lr = lane & 15;
  const int rm = lr & 7;  // read-side XOR mask

  __shared__ __align__(16) bf16 sK[64][128];   // XOR-swizzled (16B slot ^= row&7)
  __shared__ __align__(16) bf16 sV[128][64];   // [d][s_local], XOR-swizzled
  __shared__ __align__(16) bf16 sP[8][16][72]; // per-wave P

  const int qrow = q0 + wave * 16;             // this wave's 16 q-rows start here
  const bf16* qbase = Qn + ((size_t)(b * Hc + h) * Sc + qrow + lr) * Dc;
  bf16x8 qf[4];
  #pragma unroll
  for (int kk = 0; kk < 4; ++kk) qf[kk] = *(const bf16x8*)(qbase + kk * 32 + lg * 8);

  f32x4 oacc[8];
  #pragma unroll
  for (int i = 0; i < 8; ++i) oacc[i] = (f32x4){0.f, 0.f, 0.f, 0.f};
  float m_run[4], l_run[4];
  #pragma unroll
  for (int r = 0; r < 4; ++r) { m_run[r] = -3.0e38f; l_run[r] = 0.f; }

  const bf16* kb = Kn + ((size_t)(b * KVc + kv) * Sc) * Dc;
  const bf16* vb = Vt + ((size_t)(b * KVc + kv) * Dc) * Sc;
  const float scl = 0.08838834764831845f * 1.4426950408889634f;  // 1/sqrt(D)*log2(e)

  const int nt = 2 * qi + 2;
  for (int t = 0; t < nt; ++t) {
    const int k0 = t * 64;
    // stage K (64x128) and V^T (128x64): linear LDS dest, inverse-swizzled source
    #pragma unroll
    for (int it = 0; it < 2; ++it) {
      int idx = it * 512 + tid;
      int r = idx >> 4, ps = idx & 15;
      int ls = ps ^ (r & 7);
      gl_lds16(kb + (size_t)(k0 + r) * Dc + ls * 8, &sK[r][ps * 8]);
    }
    #pragma unroll
    for (int it = 0; it < 2; ++it) {
      int idx = it * 512 + tid;
      int r = idx >> 3, ps = idx & 7;
      int ls = ps ^ (r & 7);
      gl_lds16(vb + (size_t)r * Sc + k0 + ls * 8, &sV[r][ps * 8]);
    }
    __syncthreads();  // vmcnt(0) drain + barrier: tile staged

    float tt[4][4];
    __builtin_amdgcn_s_setprio(1);
    #pragma unroll
    for (int c = 0; c < 4; ++c) {
      f32x4 sacc = (f32x4){0.f, 0.f, 0.f, 0.f};
      #pragma unroll
      for (int kk = 0; kk < 4; ++kk) {
        bf16x8 kf = *(const bf16x8*)&sK[c * 16 + lr][((kk * 4 + lg) ^ rm) * 8];
        sacc = MFMA16(qf[kk], kf, sacc);
      }
      int kg = k0 + c * 16 + lr;
      #pragma unroll
      for (int r = 0; r < 4; ++r) {
        int qg = qrow + lg * 4 + r;
        tt[c][r] = (kg <= qg) ? sacc[r] * scl : -3.0e38f;
      }
    }
    __builtin_amdgcn_s_setprio(0);

    // row max (16 lanes per row share via xor 1/2/4/8)
    float pmax[4];
    #pragma unroll
    for (int r = 0; r < 4; ++r) {
      float mx = fmaxf(fmaxf(tt[0][r], tt[1][r]), fmaxf(tt[2][r], tt[3][r]));
      mx = fmaxf(mx, __shfl_xor(mx, 1));
      mx = fmaxf(mx, __shfl_xor(mx, 2));
      mx = fmaxf(mx, __shfl_xor(mx, 4));
      mx = fmaxf(mx, __shfl_xor(mx, 8));
      pmax[r] = mx;
    }
    // T13 defer-max: skip rescale while max growth <= 8 (P bounded by 2^8)
    bool grow = (pmax[0] > m_run[0] + 8.f) || (pmax[1] > m_run[1] + 8.f) ||
                (pmax[2] > m_run[2] + 8.f) || (pmax[3] > m_run[3] + 8.f);
    if (__any(grow)) {
      #pragma unroll
      for (int r = 0; r < 4; ++r) {
        float mnew = fmaxf(m_run[r], pmax[r]);
        float alpha = exp2f(m_run[r] - mnew);
        m_run[r] = mnew;
        l_run[r] *= alpha;
        #pragma unroll
        for (int dc = 0; dc < 8; ++dc) oacc[dc][r] *= alpha;
      }
    }
    #pragma unroll
    for (int r = 0; r < 4; ++r) {
      float local = 0.f;
      #pragma unroll
      for (int c = 0; c < 4; ++c) { tt[c][r] = exp2f(tt[c][r] - m_run[r]); local += tt[c][r]; }
      l_run[r] += local;  // per-lane partial; reduced once after the loop
    }
    // per-wave P round-trip (same-wave LDS RAW: lgkmcnt-ordered, no barrier)
    #pragma unroll
    for (int c = 0; c < 4; ++c)
      #pragma unroll
      for (int r = 0; r < 4; ++r)
        sP[wave][lg * 4 + r][c * 16 + lr] = __float2bfloat16(tt[c][r]);

    __builtin_amdgcn_s_setprio(1);
    #pragma unroll
    for (int kk2 = 0; kk2 < 2; ++kk2) {
      bf16x8 pf = *(const bf16x8*)&sP[wave][lr][kk2 * 32 + lg * 8];
      #pragma unroll
      for (int dc = 0; dc < 8; ++dc) {
        bf16x8 vf = *(const bf16x8*)&sV[dc * 16 + lr][((kk2 * 4 + lg) ^ rm) * 8];
        oacc[dc] = MFMA16(pf, vf, oacc[dc]);
      }
    }
    __builtin_amdgcn_s_setprio(0);

    __syncthreads();  // all waves done with sK/sV before next tile overwrites
  }

  #pragma unroll
  for (int r = 0; r < 4; ++r) {
    float l = l_run[r];
    l += __shfl_xor(l, 1);
    l += __shfl_xor(l, 2);
    l += __shfl_xor(l, 4);
    l += __shfl_xor(l, 8);
    l_run[r] = 1.f / l;
  }
  #pragma unroll
  for (int dc = 0; dc < 8; ++dc)
    #pragma unroll
    for (int r = 0; r < 4; ++r) {
      size_t row = (size_t)b * Sc + qrow + lg * 4 + r;
      Out[row * (size_t)(Hc * Dc) + h * Dc + dc * 16 + lr] =
          __float2bfloat16(oacc[dc][r] * l_run[r]);
    }
}

// ---------------- launch ----------------
extern "C" void kernel_launch(void* const* d_in, const int* in_sizes, int n_in,
                              void* d_out, int out_size, void* d_ws, size_t ws_size,
                              hipStream_t stream) {
  const float* x    = (const float*)d_in[0];
  const float* cosT = (const float*)d_in[1];
  const float* sinT = (const float*)d_in[2];
  const float* wq   = (const float*)d_in[3];
  const float* wk   = (const float*)d_in[4];
  const float* wv   = (const float*)d_in[5];
  const float* wo   = (const float*)d_in[6];
  const float* qnw  = (const float*)d_in[7];
  const float* knw  = (const float*)d_in[8];
  float* out = (float*)d_out;

  const size_t MB = 1ull << 20;
  char* ws = (char*)d_ws;
  bf16* xb   = (bf16*)(ws + 0);        // 32MB  [8192][2048]
  bf16* wqkv = (bf16*)(ws + 32 * MB);  // 16MB  [4096][2048]
  bf16* wob  = (bf16*)(ws + 48 * MB);  // 8MB   [2048][2048]
  bf16* qkv  = (bf16*)(ws + 56 * MB);  // 64MB  [8192][4096]
  bf16* Qn   = (bf16*)(ws + 120 * MB); // 32MB  [B][H][S][D]
  bf16* Kn   = (bf16*)(ws + 152 * MB); // 16MB  [B][KV][S][D]
  bf16* Vt   = (bf16*)(ws + 168 * MB); // 16MB  [B][KV][D][S]
  bf16* attn = (bf16*)(ws + 184 * MB); // 32MB  [8192][2048]

  cvt_all<<<2048, 256, 0, stream>>>(x, wq, wk, wv, wo,
                                    (unsigned short*)xb, (unsigned short*)wqkv,
                                    (unsigned short*)wob);

  // QKV GEMM: grid 64x32 blocks -> 1D, region 32x8 (B-slice 4MB/XCD-L2)
  gemm_bt<bf16><<<2048, 256, 0, stream>>>(xb, wqkv, qkv, 8192, 4096, 2048, 64, 32, 32, 8);
  norm_rope<<<8192, 256, 0, stream>>>(qkv, cosT, sinT, qnw, knw, Qn, Kn);
  v_transpose<<<dim3(32, 32), 256, 0, stream>>>(qkv, Vt);
  flash_kernel<<<1024, 512, 0, stream>>>(Qn, Kn, Vt, attn);
  // out GEMM: grid 64x16 -> 1D, region 32x4 (B-slice 2MB)
  gemm_bt<float><<<1024, 256, 0, stream>>>(attn, wob, out, 8192, 2048, 2048, 64, 16, 32, 4);
}

// Round 6
// 384.401 us; speedup vs baseline: 2.1107x; 1.2662x over previous
//
#include <hip/hip_runtime.h>
#include <hip/hip_bf16.h>
#include <stdint.h>

using bf16 = __hip_bfloat16;
typedef __attribute__((ext_vector_type(8))) short bf16x8;
typedef __attribute__((ext_vector_type(4))) float f32x4;
typedef __attribute__((ext_vector_type(8))) unsigned short ushort8;

#define MFMA16(a,b,c) __builtin_amdgcn_mfma_f32_16x16x32_bf16(a,b,c,0,0,0)

static constexpr int Bc = 4, Sc = 2048, HSc = 2048, Hc = 16, KVc = 8, Dc = 128;

__device__ __forceinline__ void gl_lds16(const void* g, void* l) {
  __builtin_amdgcn_global_load_lds((const __attribute__((address_space(1))) uint32_t*)g,
                                   (__attribute__((address_space(3))) uint32_t*)l, 16, 0, 0);
}

__device__ __forceinline__ unsigned short f2bf(float f) {
  bf16 h = __float2bfloat16(f);
  return *reinterpret_cast<unsigned short*>(&h);
}

// ---------------- fused fp32 -> bf16 convert ----------------
__global__ __launch_bounds__(256) void cvt_all(const float* __restrict__ x,
                                               const float* __restrict__ wq,
                                               const float* __restrict__ wk,
                                               const float* __restrict__ wv,
                                               const float* __restrict__ wo,
                                               unsigned short* __restrict__ xb,
                                               unsigned short* __restrict__ wqkv,
                                               unsigned short* __restrict__ wob) {
  const int NX = 2097152, NQ = 524288, NK = 262144, NV = 262144, NO = 524288;
  const int T = NX + NQ + NK + NV + NO;
  int stride = gridDim.x * blockDim.x;
  for (int i = blockIdx.x * blockDim.x + threadIdx.x; i < T; i += stride) {
    const float* s;
    unsigned short* d;
    int j = i;
    if (j < NX) { s = x; d = xb; }
    else if ((j -= NX) < NQ) { s = wq; d = wqkv; }
    else if ((j -= NQ) < NK) { s = wk; d = wqkv + (size_t)NQ * 8; }
    else if ((j -= NK) < NV) { s = wv; d = wqkv + (size_t)(NQ + NK) * 8; }
    else { j -= NV; s = wo; d = wob; }
    const float4 a = *(const float4*)(s + (size_t)j * 8);
    const float4 b = *(const float4*)(s + (size_t)j * 8 + 4);
    ushort8 o;
    o[0] = f2bf(a.x); o[1] = f2bf(a.y); o[2] = f2bf(a.z); o[3] = f2bf(a.w);
    o[4] = f2bf(b.x); o[5] = f2bf(b.y); o[6] = f2bf(b.z); o[7] = f2bf(b.w);
    *(ushort8*)(d + (size_t)j * 8) = o;
  }
}

__device__ __forceinline__ void storeC(float* C, size_t i, float v) { C[i] = v; }
__device__ __forceinline__ void storeC(bf16* C, size_t i, float v) { C[i] = __float2bfloat16(v); }

// ---------------- 256x256 8-phase GEMM: C[M][N] = A[M][K] * B[N][K]^T ----------------
// T2 (XOR-swizzled LDS via inverse-swizzled gload source), T3+T4 (8-phase with
// counted vmcnt(4) at P4/P8 only), T5 (setprio around MFMA clusters), T1 (XCD regions).
// Stage ledger (verified): P1:A0(t+1) P2:A1(t+1) P3:B0(t+2) P4:B1(t+2)
//                          P5:A0(t+2) P6:A1(t+2) P7:B0(t+3) P8:B1(t+3)
// vmcnt(4)@P4 -> t+1 fully landed (outstanding = P3,P4 halves only).
// vmcnt(4)@P8 -> t+2 fully landed. Every stage targets a slot last read >=1 barrier ago.

#define LDA_(MI, BUF)                                                          \
  _Pragma("unroll") for (int rf = 0; rf < 4; ++rf)                             \
  _Pragma("unroll") for (int k = 0; k < 2; ++k) {                              \
    const int row_ = (MI * 4 + rf) * 16 + lr;                                  \
    a[rf][k] = *(const bf16x8*)&sA[BUF][wm][row_][((k * 4 + lg) ^ (row_ & 7)) * 8]; \
  }
#define LDB_(NI, BUF, BREG)                                                    \
  _Pragma("unroll") for (int j = 0; j < 2; ++j)                                \
  _Pragma("unroll") for (int k = 0; k < 2; ++k) {                              \
    const int row_ = (bco + NI * 2 + j) * 16 + lr;                             \
    BREG[j][k] = *(const bf16x8*)&sB[BUF][bh][row_][((k * 4 + lg) ^ (row_ & 7)) * 8]; \
  }
#define MM_(MI, NI, BREG)                                                      \
  __builtin_amdgcn_s_setprio(1);                                               \
  _Pragma("unroll") for (int rf = 0; rf < 4; ++rf)                             \
  _Pragma("unroll") for (int j = 0; j < 2; ++j)                                \
  _Pragma("unroll") for (int k = 0; k < 2; ++k)                                \
    acc[MI * 4 + rf][NI * 2 + j] =                                             \
        MFMA16(a[rf][k], BREG[j][k], acc[MI * 4 + rf][NI * 2 + j]);            \
  __builtin_amdgcn_s_setprio(0);
#define BAR_ __builtin_amdgcn_s_barrier();
#define VM4_ asm volatile("s_waitcnt vmcnt(4)" ::: "memory");
#define VM0_ asm volatile("s_waitcnt vmcnt(0)" ::: "memory");

template <typename OUT_T>
__global__ __launch_bounds__(512, 2) void gemm8(const bf16* __restrict__ A,
                                                const bf16* __restrict__ B,
                                                OUT_T* __restrict__ C,
                                                int M, int N, int K,
                                                int gm, int gn, int rbm, int rbn) {
  const int nwg = gridDim.x;
  const int cpx = nwg >> 3;
  const int swz = (blockIdx.x & 7) * cpx + (blockIdx.x >> 3);
  const int rsz = rbm * rbn;
  const int region = swz / rsz, rid = swz % rsz;
  const int regions_n = gn / rbn;
  const int bm = (region / regions_n) * rbm + rid / rbn;
  const int bn = (region % regions_n) * rbn + rid % rbn;

  __shared__ __align__(16) bf16 sA[2][2][128][64];  // [buf][half][row][k] 64KB
  __shared__ __align__(16) bf16 sB[2][2][128][64];  // 64KB

  const int tid = threadIdx.x;
  const int lane = tid & 63;
  const int wave = tid >> 6;      // 0..7
  const int wm = wave >> 2;       // 0..1 : A half
  const int wn = wave & 3;        // 0..3
  const int lg = lane >> 4, lr = lane & 15;
  const int bh = wn >> 1;         // wave's B half
  const int bco = (wn & 1) * 4;   // colfrag base within half

  const int rowA = bm * 256;
  const int colB = bn * 256;
  const int NT = K >> 6;

  f32x4 acc[8][4];
  #pragma unroll
  for (int i = 0; i < 8; ++i)
    #pragma unroll
    for (int j = 0; j < 4; ++j) acc[i][j] = (f32x4){0.f, 0.f, 0.f, 0.f};

  auto stA = [&](int buf, int half, int kt) {
    const bf16* src = A + (size_t)(rowA + half * 128) * K + kt * 64;
    #pragma unroll
    for (int is = 0; is < 2; ++is) {
      int r = is * 64 + (tid >> 3);
      int sl = (tid & 7) ^ (r & 7);
      gl_lds16(src + (size_t)r * K + sl * 8, &sA[buf][half][r][(tid & 7) * 8]);
    }
  };
  auto stB = [&](int buf, int half, int kt) {
    const bf16* src = B + (size_t)(colB + half * 128) * K + kt * 64;
    #pragma unroll
    for (int is = 0; is < 2; ++is) {
      int r = is * 64 + (tid >> 3);
      int sl = (tid & 7) ^ (r & 7);
      gl_lds16(src + (size_t)r * K + sl * 8, &sB[buf][half][r][(tid & 7) * 8]);
    }
  };

  // prologue: all of t0, B halves of t1; wait for t0 (8 oldest of 12 loads)
  stB(0, 0, 0); stB(0, 1, 0); stA(0, 0, 0); stA(0, 1, 0);
  stB(1, 0, 1); stB(1, 1, 1);
  VM4_
  __builtin_amdgcn_s_barrier();

  for (int t = 0; t < NT; t += 2) {
    const bool lastit = (t + 2 >= NT);
    bf16x8 a[4][2], bl[2][2], br[2][2];
    // ---------- K-tile t (buf0) ----------
    // P1
    LDA_(0, 0) LDB_(0, 0, bl)
    stA(1, 0, t + 1);
    BAR_ MM_(0, 0, bl) BAR_
    // P2
    LDB_(1, 0, br)
    stA(1, 1, t + 1);
    BAR_ MM_(0, 1, br) BAR_
    // P3
    LDA_(1, 0)
    if (!lastit) stB(0, 0, t + 2);
    BAR_ MM_(1, 0, bl) BAR_
    // P4
    if (!lastit) stB(0, 1, t + 2);
    BAR_ MM_(1, 1, br)
    if (lastit) { VM0_ } else { VM4_ }
    BAR_
    // ---------- K-tile t+1 (buf1) ----------
    // P5
    LDA_(0, 1) LDB_(0, 1, bl)
    if (!lastit) stA(0, 0, t + 2);
    BAR_ MM_(0, 0, bl) BAR_
    // P6
    LDB_(1, 1, br)
    if (!lastit) stA(0, 1, t + 2);
    BAR_ MM_(0, 1, br) BAR_
    // P7
    LDA_(1, 1)
    if (t + 3 < NT) stB(1, 0, t + 3);
    BAR_ MM_(1, 0, bl) BAR_
    // P8
    if (t + 3 < NT) stB(1, 1, t + 3);
    BAR_ MM_(1, 1, br)
    if (!lastit) { VM4_ }
    BAR_
  }

  #pragma unroll
  for (int rf = 0; rf < 8; ++rf)
    #pragma unroll
    for (int cf = 0; cf < 4; ++cf)
      #pragma unroll
      for (int r = 0; r < 4; ++r) {
        size_t row = rowA + wm * 128 + rf * 16 + lg * 4 + r;
        size_t col = colB + wn * 64 + cf * 16 + lr;
        storeC(C, row * (size_t)N + col, acc[rf][cf][r]);
      }
}

// ---------------- RMSNorm + RoPE on Q and K ----------------
__global__ __launch_bounds__(256) void norm_rope(const bf16* __restrict__ qkv,
                                                 const float* __restrict__ cosT,
                                                 const float* __restrict__ sinT,
                                                 const float* __restrict__ qw,
                                                 const float* __restrict__ kw,
                                                 bf16* __restrict__ Qn, bf16* __restrict__ Kn) {
  const int bs = blockIdx.x;
  const int s = bs & (Sc - 1);
  const int b = bs >> 11;
  const int wave = threadIdx.x >> 6, lane = threadIdx.x & 63;
  const float c0 = cosT[(size_t)s * Dc + lane];
  const float c1 = cosT[(size_t)s * Dc + 64 + lane];
  const float s0 = sinT[(size_t)s * Dc + lane];
  const float s1 = sinT[(size_t)s * Dc + 64 + lane];
  const bf16* row = qkv + (size_t)bs * 4096;
  #pragma unroll
  for (int i = 0; i < 6; ++i) {
    int head = wave * 6 + i;  // 0..15 = Q heads, 16..23 = K heads
    bool isQ = head < 16;
    int col = head * Dc;
    float x0 = __bfloat162float(row[col + lane]);
    float x1 = __bfloat162float(row[col + 64 + lane]);
    float ss = x0 * x0 + x1 * x1;
    #pragma unroll
    for (int off = 32; off; off >>= 1) ss += __shfl_xor(ss, off);
    float inv = rsqrtf(ss * (1.0f / 128.0f) + 1e-6f);
    const float* w = isQ ? qw : kw;
    float n0 = x0 * inv * w[lane];
    float n1 = x1 * inv * w[lane + 64];
    float o0 = n0 * c0 - n1 * s0;
    float o1 = n1 * c1 + n0 * s1;
    size_t base;
    bf16* dst;
    if (isQ) { base = ((size_t)(b * Hc + head) * Sc + s) * Dc; dst = Qn; }
    else     { base = ((size_t)(b * KVc + (head - 16)) * Sc + s) * Dc; dst = Kn; }
    dst[base + lane] = __float2bfloat16(o0);
    dst[base + 64 + lane] = __float2bfloat16(o1);
  }
}

// ---------------- V transpose: qkv V slice -> Vt [B][KV][D][S] ----------------
__global__ __launch_bounds__(256) void v_transpose(const bf16* __restrict__ qkv,
                                                   bf16* __restrict__ Vt) {
  const int s0 = blockIdx.x * 64;
  const int bk = blockIdx.y;  // b*8+kv
  __shared__ __align__(16) bf16 tile[64][136];
  const int tid = threadIdx.x;
  const size_t srcbase = ((size_t)(bk >> 3) * Sc + s0) * 4096 + 3072 + (size_t)(bk & 7) * Dc;
  #pragma unroll
  for (int it = 0; it < 4; ++it) {
    int idx = it * 256 + tid;
    int r = idx >> 4, ch = idx & 15;
    *(bf16x8*)&tile[r][ch * 8] = *(const bf16x8*)(qkv + srcbase + (size_t)r * 4096 + ch * 8);
  }
  __syncthreads();
  const size_t dstbase = (size_t)bk * Dc * Sc + s0;
  #pragma unroll
  for (int it = 0; it < 4; ++it) {
    int idx = it * 256 + tid;
    int d = idx >> 3, scc = idx & 7;
    bf16x8 o;
    #pragma unroll
    for (int j = 0; j < 8; ++j) o[j] = *(const short*)&tile[scc * 8 + j][d];
    *(bf16x8*)(Vt + dstbase + (size_t)d * Sc + scc * 8) = o;
  }
}

// ---------------- causal GQA flash attention ----------------
// QBLK=128, 8 waves, single-buffered, T2 swizzle, heavy-first, T5, T13.
__global__ __launch_bounds__(512, 4) void flash_kernel(const bf16* __restrict__ Qn,
                                                       const bf16* __restrict__ Kn,
                                                       const bf16* __restrict__ Vt,
                                                       bf16* __restrict__ Out) {
  const int qi = 15 - (blockIdx.x >> 6);
  const int bh = blockIdx.x & 63;
  const int q0 = qi * 128;
  const int b = bh >> 4, h = bh & 15;
  const int kv = h >> 1;
  const int tid = threadIdx.x;
  const int wave = tid >> 6, lane = tid & 63;
  const int lg = lane >> 4, lr = lane & 15;
  const int rm = lr & 7;

  __shared__ __align__(16) bf16 sK[64][128];
  __shared__ __align__(16) bf16 sV[128][64];
  __shared__ __align__(16) bf16 sP[8][16][72];

  const int qrow = q0 + wave * 16;
  const bf16* qbase = Qn + ((size_t)(b * Hc + h) * Sc + qrow + lr) * Dc;
  bf16x8 qf[4];
  #pragma unroll
  for (int kk = 0; kk < 4; ++kk) qf[kk] = *(const bf16x8*)(qbase + kk * 32 + lg * 8);

  f32x4 oacc[8];
  #pragma unroll
  for (int i = 0; i < 8; ++i) oacc[i] = (f32x4){0.f, 0.f, 0.f, 0.f};
  float m_run[4], l_run[4];
  #pragma unroll
  for (int r = 0; r < 4; ++r) { m_run[r] = -3.0e38f; l_run[r] = 0.f; }

  const bf16* kb = Kn + ((size_t)(b * KVc + kv) * Sc) * Dc;
  const bf16* vb = Vt + ((size_t)(b * KVc + kv) * Dc) * Sc;
  const float scl = 0.08838834764831845f * 1.4426950408889634f;

  const int nt = 2 * qi + 2;
  for (int t = 0; t < nt; ++t) {
    const int k0 = t * 64;
    #pragma unroll
    for (int it = 0; it < 2; ++it) {
      int idx = it * 512 + tid;
      int r = idx >> 4, ps = idx & 15;
      int ls = ps ^ (r & 7);
      gl_lds16(kb + (size_t)(k0 + r) * Dc + ls * 8, &sK[r][ps * 8]);
    }
    #pragma unroll
    for (int it = 0; it < 2; ++it) {
      int idx = it * 512 + tid;
      int r = idx >> 3, ps = idx & 7;
      int ls = ps ^ (r & 7);
      gl_lds16(vb + (size_t)r * Sc + k0 + ls * 8, &sV[r][ps * 8]);
    }
    __syncthreads();

    float tt[4][4];
    __builtin_amdgcn_s_setprio(1);
    #pragma unroll
    for (int c = 0; c < 4; ++c) {
      f32x4 sacc = (f32x4){0.f, 0.f, 0.f, 0.f};
      #pragma unroll
      for (int kk = 0; kk < 4; ++kk) {
        bf16x8 kf = *(const bf16x8*)&sK[c * 16 + lr][((kk * 4 + lg) ^ rm) * 8];
        sacc = MFMA16(qf[kk], kf, sacc);
      }
      int kg = k0 + c * 16 + lr;
      #pragma unroll
      for (int r = 0; r < 4; ++r) {
        int qg = qrow + lg * 4 + r;
        tt[c][r] = (kg <= qg) ? sacc[r] * scl : -3.0e38f;
      }
    }
    __builtin_amdgcn_s_setprio(0);

    float pmax[4];
    #pragma unroll
    for (int r = 0; r < 4; ++r) {
      float mx = fmaxf(fmaxf(tt[0][r], tt[1][r]), fmaxf(tt[2][r], tt[3][r]));
      mx = fmaxf(mx, __shfl_xor(mx, 1));
      mx = fmaxf(mx, __shfl_xor(mx, 2));
      mx = fmaxf(mx, __shfl_xor(mx, 4));
      mx = fmaxf(mx, __shfl_xor(mx, 8));
      pmax[r] = mx;
    }
    bool grow = (pmax[0] > m_run[0] + 8.f) || (pmax[1] > m_run[1] + 8.f) ||
                (pmax[2] > m_run[2] + 8.f) || (pmax[3] > m_run[3] + 8.f);
    if (__any(grow)) {
      #pragma unroll
      for (int r = 0; r < 4; ++r) {
        float mnew = fmaxf(m_run[r], pmax[r]);
        float alpha = exp2f(m_run[r] - mnew);
        m_run[r] = mnew;
        l_run[r] *= alpha;
        #pragma unroll
        for (int dc = 0; dc < 8; ++dc) oacc[dc][r] *= alpha;
      }
    }
    #pragma unroll
    for (int r = 0; r < 4; ++r) {
      float local = 0.f;
      #pragma unroll
      for (int c = 0; c < 4; ++c) { tt[c][r] = exp2f(tt[c][r] - m_run[r]); local += tt[c][r]; }
      l_run[r] += local;
    }
    #pragma unroll
    for (int c = 0; c < 4; ++c)
      #pragma unroll
      for (int r = 0; r < 4; ++r)
        sP[wave][lg * 4 + r][c * 16 + lr] = __float2bfloat16(tt[c][r]);

    __builtin_amdgcn_s_setprio(1);
    #pragma unroll
    for (int kk2 = 0; kk2 < 2; ++kk2) {
      bf16x8 pf = *(const bf16x8*)&sP[wave][lr][kk2 * 32 + lg * 8];
      #pragma unroll
      for (int dc = 0; dc < 8; ++dc) {
        bf16x8 vf = *(const bf16x8*)&sV[dc * 16 + lr][((kk2 * 4 + lg) ^ rm) * 8];
        oacc[dc] = MFMA16(pf, vf, oacc[dc]);
      }
    }
    __builtin_amdgcn_s_setprio(0);

    __syncthreads();
  }

  #pragma unroll
  for (int r = 0; r < 4; ++r) {
    float l = l_run[r];
    l += __shfl_xor(l, 1);
    l += __shfl_xor(l, 2);
    l += __shfl_xor(l, 4);
    l += __shfl_xor(l, 8);
    l_run[r] = 1.f / l;
  }
  #pragma unroll
  for (int dc = 0; dc < 8; ++dc)
    #pragma unroll
    for (int r = 0; r < 4; ++r) {
      size_t row = (size_t)b * Sc + qrow + lg * 4 + r;
      Out[row * (size_t)(Hc * Dc) + h * Dc + dc * 16 + lr] =
          __float2bfloat16(oacc[dc][r] * l_run[r]);
    }
}

// ---------------- launch ----------------
extern "C" void kernel_launch(void* const* d_in, const int* in_sizes, int n_in,
                              void* d_out, int out_size, void* d_ws, size_t ws_size,
                              hipStream_t stream) {
  const float* x    = (const float*)d_in[0];
  const float* cosT = (const float*)d_in[1];
  const float* sinT = (const float*)d_in[2];
  const float* wq   = (const float*)d_in[3];
  const float* wk   = (const float*)d_in[4];
  const float* wv   = (const float*)d_in[5];
  const float* wo   = (const float*)d_in[6];
  const float* qnw  = (const float*)d_in[7];
  const float* knw  = (const float*)d_in[8];
  float* out = (float*)d_out;

  const size_t MB = 1ull << 20;
  char* ws = (char*)d_ws;
  bf16* xb   = (bf16*)(ws + 0);        // 32MB  [8192][2048]
  bf16* wqkv = (bf16*)(ws + 32 * MB);  // 16MB  [4096][2048]
  bf16* wob  = (bf16*)(ws + 48 * MB);  // 8MB   [2048][2048]
  bf16* qkv  = (bf16*)(ws + 56 * MB);  // 64MB  [8192][4096]
  bf16* Qn   = (bf16*)(ws + 120 * MB); // 32MB  [B][H][S][D]
  bf16* Kn   = (bf16*)(ws + 152 * MB); // 16MB  [B][KV][S][D]
  bf16* Vt   = (bf16*)(ws + 168 * MB); // 16MB  [B][KV][D][S]
  bf16* attn = (bf16*)(ws + 184 * MB); // 32MB  [8192][2048]

  cvt_all<<<2048, 256, 0, stream>>>(x, wq, wk, wv, wo,
                                    (unsigned short*)xb, (unsigned short*)wqkv,
                                    (unsigned short*)wob);

  // QKV GEMM: 32x16 blocks of 256x256; XCD region 16x4 (B-slice 4MB L2-fits)
  gemm8<bf16><<<512, 512, 0, stream>>>(xb, wqkv, qkv, 8192, 4096, 2048, 32, 16, 16, 4);
  norm_rope<<<8192, 256, 0, stream>>>(qkv, cosT, sinT, qnw, knw, Qn, Kn);
  v_transpose<<<dim3(32, 32), 256, 0, stream>>>(qkv, Vt);
  flash_kernel<<<1024, 512, 0, stream>>>(Qn, Kn, Vt, attn);
  // out GEMM: 32x8 blocks; region 8x4 (B-slice 4MB)
  gemm8<float><<<256, 512, 0, stream>>>(attn, wob, out, 8192, 2048, 2048, 32, 8, 8, 4);
}